// Round 7
// baseline (239.265 us; speedup 1.0000x reference)
//
#include <hip/hip_runtime.h>
#include <cmath>

#define LOG2E 1.4426950408889634f

typedef __attribute__((ext_vector_type(8))) __bf16 bf16x8;
typedef __attribute__((ext_vector_type(4))) float f32x4;
typedef __attribute__((ext_vector_type(16))) float f32x16;
typedef __attribute__((ext_vector_type(4))) float float4v;
typedef __attribute__((ext_vector_type(8))) unsigned short ushort8;
typedef __attribute__((ext_vector_type(4))) unsigned int uint4v;
typedef __attribute__((ext_vector_type(2))) int int2v;

__device__ __forceinline__ unsigned short f2bf(float f) {
  unsigned int u = __builtin_bit_cast(unsigned int, f);
  u += 0x7fffu + ((u >> 16) & 1u);   // RNE
  return (unsigned short)(u >> 16);
}

__device__ __forceinline__ unsigned int cvtpk(float lo, float hi) {
  unsigned int r;
  asm volatile("v_cvt_pk_bf16_f32 %0, %1, %2" : "=v"(r) : "v"(lo), "v"(hi));
  return r;
}

// ---------- kernel 1: Wt[w][n][k] = bf16(W_w[k][n] * (w==0 ? LOG2E/16 : 1)) ----------
__global__ __launch_bounds__(256) void prep_w_kernel(
    const float* __restrict__ Wq, const float* __restrict__ Wk,
    const float* __restrict__ Wv, unsigned short* __restrict__ Wt) {
  const int w = blockIdx.y, n = blockIdx.x, k = threadIdx.x;
  const float* W = (w == 0) ? Wq : ((w == 1) ? Wk : Wv);
  const float s = (w == 0) ? (LOG2E / 16.0f) : 1.0f;
  Wt[w * 65536 + n * 256 + k] = f2bf(W[k * 256 + n] * s);
}

// ---------- kernel 2: fused q/k/v projection ----------
// grid (256, 2): nf-half split -> 512 blocks -> 2 blocks/CU; per nf, the 3
// weight matrices form 3 independent MFMA chains (ILP on B-loads).
__global__ __launch_bounds__(256) void proj_kernel(
    const float* __restrict__ x, const unsigned short* __restrict__ Wt,
    const float* __restrict__ bq, const float* __restrict__ bk,
    const float* __restrict__ bv,
    unsigned short* __restrict__ q_o, unsigned short* __restrict__ k_o,
    unsigned short* __restrict__ vt_o) {
  const int mt = blockIdx.x;           // 256 m-tiles of 64 rows
  const int nfh = blockIdx.y;          // nf half
  const int tid = threadIdx.x;
  const int wid = tid >> 6, lane = tid & 63, g = (lane >> 4) & 3, c = lane & 15;
  const int row_base = mt * 64 + wid * 16;

  bf16x8 a[8];
  const float* xr = x + (size_t)(row_base + c) * 256;
#pragma unroll
  for (int s = 0; s < 8; ++s) {
    const float4v v0 = *(const float4v*)(xr + s * 32 + g * 8);
    const float4v v1 = *(const float4v*)(xr + s * 32 + g * 8 + 4);
    union { bf16x8 v; unsigned short u[8]; } t;
#pragma unroll
    for (int j = 0; j < 4; ++j) { t.u[j] = f2bf(v0[j]); t.u[4 + j] = f2bf(v1[j]); }
    a[s] = t.v;
  }

  const unsigned short* w0 = Wt;
  const unsigned short* w1 = Wt + 65536;
  const unsigned short* w2 = Wt + 131072;

#pragma unroll
  for (int nfi = 0; nfi < 8; ++nfi) {
    const int nf = nfh * 8 + nfi;
    f32x4 aq = (f32x4){0.f, 0.f, 0.f, 0.f};
    f32x4 ak = (f32x4){0.f, 0.f, 0.f, 0.f};
    f32x4 av = (f32x4){0.f, 0.f, 0.f, 0.f};
    const unsigned short* r0 = w0 + (size_t)(nf * 16 + c) * 256;
    const unsigned short* r1 = w1 + (size_t)(nf * 16 + c) * 256;
    const unsigned short* r2 = w2 + (size_t)(nf * 16 + c) * 256;
#pragma unroll
    for (int s = 0; s < 8; ++s) {
      bf16x8 b0 = *(const bf16x8*)(r0 + s * 32 + g * 8);
      bf16x8 b1 = *(const bf16x8*)(r1 + s * 32 + g * 8);
      bf16x8 b2 = *(const bf16x8*)(r2 + s * 32 + g * 8);
      aq = __builtin_amdgcn_mfma_f32_16x16x32_bf16(a[s], b0, aq, 0, 0, 0);
      ak = __builtin_amdgcn_mfma_f32_16x16x32_bf16(a[s], b1, ak, 0, 0, 0);
      av = __builtin_amdgcn_mfma_f32_16x16x32_bf16(a[s], b2, av, 0, 0, 0);
    }
    const float bql = bq[nf * 16 + c] * (LOG2E / 16.0f);
    const float bkl = bk[nf * 16 + c];
    const float bvl = bv[nf * 16 + c];
#pragma unroll
    for (int r = 0; r < 4; ++r) {
      const int row = row_base + g * 4 + r;
      q_o[(size_t)row * 256 + nf * 16 + c] = f2bf(aq[r] + bql);
      k_o[(size_t)row * 256 + nf * 16 + c] = f2bf(ak[r] + bkl);
      const int b_ = row >> 12, s_ = row & 4095;
      vt_o[((size_t)b_ * 256 + nf * 16 + c) * 4096 + s_] = f2bf(av[r] + bvl);
    }
  }
}

// ---------- kernel 3: causal flash attention ----------
// 512 blocks = 4 batches x 128 q-tiles of 32 rows; blocks c and c+256 land on
// the same CU (round-robin) and their step counts sum to exactly 65.
// 64KB LDS single-buffer -> 2 blocks/CU. Staging = T14 async split:
// global->regs issued BEFORE compute (latency hides under MFMA), swizzled
// ds_write after the read barrier. setprio(1) around MFMA clusters (T5).
__global__ __launch_bounds__(256, 2) void attn_kernel(
    const unsigned short* __restrict__ qg, const unsigned short* __restrict__ kg,
    const unsigned short* __restrict__ vtg, float* __restrict__ out) {
  __shared__ unsigned short Klds[64 * 256];   // 32KB, swizzled
  __shared__ unsigned short Vlds[256 * 64];   // 32KB, swizzled
  __shared__ float llds[2][32];

  const int tid = threadIdx.x;
  const int wid = tid >> 6, lane = tid & 63;
  const int hi = lane >> 5, q5 = lane & 31;
  const int wk = wid & 1, dh = wid >> 1;
  const int bid = blockIdx.x;
  const int half = bid >> 8, k6 = (bid >> 2) & 63, b = bid & 3;
  const int qt = half ? k6 : 127 - k6;
  const int T = (qt >> 1) + 1;

  const unsigned short* qb = qg + (size_t)b * 4096 * 256;
  const unsigned short* kb = kg + (size_t)b * 4096 * 256;
  const unsigned short* vb = vtg + (size_t)b * 256 * 4096;
  float* outb = out + (size_t)b * 4096 * 256;

  const int q0 = qt * 32;
  const int qrow = q0 + q5;

  // ---- T14 staging: global->regs (issue early), swizzled ds_write (late) ----
  uint4v kst[8], vst[8];
  const int krp = lane >> 5, kc8 = lane & 31;   // K: chunk row parity, col slot
  const int vrp = lane >> 3, vc8 = lane & 7;    // V: row-in-chunk, col slot

  auto load_tiles = [&](int t) {
#pragma unroll
    for (int i = 0; i < 8; ++i) {
      const int kr = (wid * 8 + i) * 2 + krp;
      kst[i] = *(const uint4v*)(kb + (size_t)t * 16384 + kr * 256 + kc8 * 8);
      const int d = (wid * 8 + i) * 8 + vrp;
      vst[i] = *(const uint4v*)(vb + (size_t)d * 4096 + t * 64 + vc8 * 8);
    }
    __builtin_amdgcn_sched_barrier(0);   // pin load issue before compute
  };
  auto write_tiles = [&]() {
#pragma unroll
    for (int i = 0; i < 8; ++i) {
      const int kr = (wid * 8 + i) * 2 + krp;
      *(uint4v*)(&Klds[kr * 256 + (kc8 ^ (kr & 7)) * 8]) = kst[i];
      const int d = (wid * 8 + i) * 8 + vrp;
      *(uint4v*)(&Vlds[d * 64 + (vc8 ^ (d & 7)) * 8]) = vst[i];
    }
  };

  // Q B-fragments (16): lane: q-col = q5, kdim = s*16 + hi*8 + jj
  bf16x8 bqf[16];
  {
    const unsigned short* qr = qb + (size_t)qrow * 256;
#pragma unroll
    for (int s = 0; s < 16; ++s) bqf[s] = *(const bf16x8*)(qr + s * 16 + hi * 8);
  }

  float l = 0.f;                     // per-lane partial row-sum (strip wk)
  f32x16 o[4];                       // O^T for d-half dh
#pragma unroll
  for (int d = 0; d < 4; ++d)
#pragma unroll
    for (int r = 0; r < 16; ++r) o[d][r] = 0.f;

  const int krow = wk * 32 + q5;
  const int ksw = (krow & 7) << 3;
  const int kbase = krow * 256;

  int kcolr[16];
#pragma unroll
  for (int r = 0; r < 16; ++r) kcolr[r] = wk * 32 + (r & 3) + 8 * (r >> 2) + 4 * hi;

  // prologue: stage tile 0
  load_tiles(0);
  write_tiles();
  __syncthreads();

  for (int t = 0; t < T; ++t) {
    const bool pf = (t + 1 < T);
    if (pf) load_tiles(t + 1);       // in flight during compute

    // ---- QK^T (swapped): S^T[k strip 32][q 32], 2 indep chains ----
    f32x16 sa, sb;
#pragma unroll
    for (int r = 0; r < 16; ++r) { sa[r] = 0.f; sb[r] = 0.f; }
    __builtin_amdgcn_s_setprio(1);
#pragma unroll
    for (int s = 0; s < 8; ++s) {
      bf16x8 ka0 = *(const bf16x8*)(&Klds[(kbase + s * 16 + hi * 8) ^ ksw]);
      bf16x8 ka1 = *(const bf16x8*)(&Klds[(kbase + (s + 8) * 16 + hi * 8) ^ ksw]);
      sa = __builtin_amdgcn_mfma_f32_32x32x16_bf16(ka0, bqf[s], sa, 0, 0, 0);
      sb = __builtin_amdgcn_mfma_f32_32x32x16_bf16(ka1, bqf[s + 8], sb, 0, 0, 0);
    }
    __builtin_amdgcn_s_setprio(0);
    f32x16 sc = sa + sb;

    // ---- causal mask (diag step only); scores already in exp2 domain ----
    if (t == T - 1) {
#pragma unroll
      for (int r = 0; r < 16; ++r)
        if (t * 64 + kcolr[r] > qrow) sc[r] = -1e30f;
    }

    // ---- P = exp2(S) (zero-max), partial row-sum ----
    float p[16];
#pragma unroll
    for (int r = 0; r < 16; ++r) p[r] = __builtin_amdgcn_exp2f(sc[r]);
    {
      float s0 = (p[0] + p[1]) + (p[2] + p[3]);
      float s1 = (p[4] + p[5]) + (p[6] + p[7]);
      float s2 = (p[8] + p[9]) + (p[10] + p[11]);
      float s3 = (p[12] + p[13]) + (p[14] + p[15]);
      l += (s0 + s1) + (s2 + s3);
    }

    // ---- build P B-fragments in-register ----
    bf16x8 pfrag[2];
#pragma unroll
    for (int s2 = 0; s2 < 2; ++s2) {
      const int base = s2 * 8;
      unsigned int X = cvtpk(p[base + 0], p[base + 1]);
      unsigned int Y = cvtpk(p[base + 2], p[base + 3]);
      unsigned int Z = cvtpk(p[base + 4], p[base + 5]);
      unsigned int W = cvtpk(p[base + 6], p[base + 7]);
#if __has_builtin(__builtin_amdgcn_permlane32_swap)
      int2v rx = __builtin_amdgcn_permlane32_swap((int)X, (int)Z, false, false);
      int2v ry = __builtin_amdgcn_permlane32_swap((int)Y, (int)W, false, false);
      uint4v u = (uint4v){(unsigned)rx[0], (unsigned)ry[0], (unsigned)rx[1], (unsigned)ry[1]};
#else
      const unsigned int Xp = __shfl_xor((int)X, 32);
      const unsigned int Yp = __shfl_xor((int)Y, 32);
      const unsigned int Zp = __shfl_xor((int)Z, 32);
      const unsigned int Wp = __shfl_xor((int)W, 32);
      uint4v u = (uint4v){hi ? Zp : X, hi ? Wp : Y, hi ? Z : Xp, hi ? W : Yp};
#endif
      pfrag[s2] = __builtin_bit_cast(bf16x8, u);
    }

    // ---- PV (swapped): O^T[d-half dh][q 32] += V^T_strip . P ----
    __builtin_amdgcn_s_setprio(1);
#pragma unroll
    for (int dblk = 0; dblk < 4; ++dblk) {
      const int drow = (dh * 4 + dblk) * 32 + q5;
      const int vsw = (drow & 7) << 3;
      const int vbase = drow * 64 + wk * 32;
#pragma unroll
      for (int s2 = 0; s2 < 2; ++s2) {
        bf16x8 va = *(const bf16x8*)(&Vlds[(vbase + s2 * 16 + hi * 8) ^ vsw]);
        o[dblk] = __builtin_amdgcn_mfma_f32_32x32x16_bf16(va, pfrag[s2], o[dblk], 0, 0, 0);
      }
    }
    __builtin_amdgcn_s_setprio(0);

    __syncthreads();                 // all waves done reading tile t
    if (pf) {
      write_tiles();                 // regs (arrived under compute) -> LDS
      __syncthreads();               // writes visible for next iter
    }
  }

  // ---- epilogue: reduce l, cross-wk O combine, write ----
  l += __shfl_xor(l, 32);
  if (dh == 0 && hi == 0) llds[wk][q5] = l;
  __syncthreads();
  const float L = llds[0][q5] + llds[1][q5];
  const float scale = 1.0f / L;

  float* oz = (float*)Klds;          // 32KB: [256 d][32 q] f32
  if (wk == 1) {
#pragma unroll
    for (int dblk = 0; dblk < 4; ++dblk)
#pragma unroll
      for (int r = 0; r < 16; ++r) {
        const int dg = (dh * 4 + dblk) * 32 + (r & 3) + 8 * (r >> 2) + 4 * hi;
        oz[dg * 32 + q5] = o[dblk][r];
      }
  }
  __syncthreads();
  if (wk == 0) {
#pragma unroll
    for (int dblk = 0; dblk < 4; ++dblk) {
#pragma unroll
      for (int q2 = 0; q2 < 4; ++q2) {
        float4v val;
#pragma unroll
        for (int e = 0; e < 4; ++e) {
          const int r = q2 * 4 + e;
          const int dg = (dh * 4 + dblk) * 32 + e + 8 * q2 + 4 * hi;
          val[e] = (o[dblk][r] + oz[dg * 32 + q5]) * scale;
        }
        *(float4v*)(outb + (size_t)qrow * 256 + (dh * 4 + dblk) * 32 + 8 * q2 + 4 * hi) = val;
      }
    }
  }
}

extern "C" void kernel_launch(void* const* d_in, const int* in_sizes, int n_in,
                              void* d_out, int out_size, void* d_ws, size_t ws_size,
                              hipStream_t stream) {
  (void)in_sizes; (void)n_in; (void)out_size; (void)ws_size;
  const float* x  = (const float*)d_in[0];
  const float* Wq = (const float*)d_in[1];
  const float* bq = (const float*)d_in[2];
  const float* Wk = (const float*)d_in[3];
  const float* bk = (const float*)d_in[4];
  const float* Wv = (const float*)d_in[5];
  const float* bv = (const float*)d_in[6];
  float* out = (float*)d_out;

  unsigned short* qs  = (unsigned short*)d_ws;                 // [4][4096][256] bf16
  unsigned short* ks  = qs  + (size_t)16384 * 256;             // [4][4096][256] bf16
  unsigned short* vts = ks  + (size_t)16384 * 256;             // [4][256][4096] bf16 (V^T)
  unsigned short* Wt  = vts + (size_t)16384 * 256;             // [3][256][256]  bf16 (W^T)

  prep_w_kernel<<<dim3(256, 3), 256, 0, stream>>>(Wq, Wk, Wv, Wt);
  proj_kernel<<<dim3(256, 2), 256, 0, stream>>>(x, Wt, bq, bk, bv, qs, ks, vts);
  attn_kernel<<<512, 256, 0, stream>>>(qs, ks, vts, out);
}

// Round 8
// 222.599 us; speedup vs baseline: 1.0749x; 1.0749x over previous
//
#include <hip/hip_runtime.h>
#include <cmath>

#define LOG2E 1.4426950408889634f

typedef __attribute__((ext_vector_type(8))) __bf16 bf16x8;
typedef __attribute__((ext_vector_type(4))) float f32x4;
typedef __attribute__((ext_vector_type(16))) float f32x16;
typedef __attribute__((ext_vector_type(4))) float float4v;
typedef __attribute__((ext_vector_type(4))) unsigned int uint4v;
typedef __attribute__((ext_vector_type(2))) int int2v;

__device__ __forceinline__ unsigned short f2bf(float f) {
  unsigned int u = __builtin_bit_cast(unsigned int, f);
  u += 0x7fffu + ((u >> 16) & 1u);   // RNE
  return (unsigned short)(u >> 16);
}

__device__ __forceinline__ unsigned int cvtpk(float lo, float hi) {
  unsigned int r;
  asm volatile("v_cvt_pk_bf16_f32 %0, %1, %2" : "=v"(r) : "v"(lo), "v"(hi));
  return r;
}

// async global->LDS, 16B per lane; LDS dest = wave-uniform base + lane*16
__device__ __forceinline__ void gload_lds16(const unsigned short* g, unsigned short* l) {
  __builtin_amdgcn_global_load_lds(
      (const __attribute__((address_space(1))) unsigned int*)(const void*)g,
      (__attribute__((address_space(3))) unsigned int*)(void*)l, 16, 0, 0);
}

// ---------- kernel 1: Wt[w][n][k] = bf16(W_w[k][n] * (w==0 ? LOG2E/16 : 1)) ----------
__global__ __launch_bounds__(256) void prep_w_kernel(
    const float* __restrict__ Wq, const float* __restrict__ Wk,
    const float* __restrict__ Wv, unsigned short* __restrict__ Wt) {
  const int w = blockIdx.y, n = blockIdx.x, k = threadIdx.x;
  const float* W = (w == 0) ? Wq : ((w == 1) ? Wk : Wv);
  const float s = (w == 0) ? (LOG2E / 16.0f) : 1.0f;
  Wt[w * 65536 + n * 256 + k] = f2bf(W[k * 256 + n] * s);
}

// ---------- kernel 2: fused q/k/v projection ----------
// grid (256, 2): nf-half split -> 2 blocks/CU; per nf, 3 independent MFMA chains.
__global__ __launch_bounds__(256) void proj_kernel(
    const float* __restrict__ x, const unsigned short* __restrict__ Wt,
    const float* __restrict__ bq, const float* __restrict__ bk,
    const float* __restrict__ bv,
    unsigned short* __restrict__ q_o, unsigned short* __restrict__ k_o,
    unsigned short* __restrict__ vt_o) {
  const int mt = blockIdx.x;           // 256 m-tiles of 64 rows
  const int nfh = blockIdx.y;          // nf half
  const int tid = threadIdx.x;
  const int wid = tid >> 6, lane = tid & 63, g = (lane >> 4) & 3, c = lane & 15;
  const int row_base = mt * 64 + wid * 16;

  bf16x8 a[8];
  const float* xr = x + (size_t)(row_base + c) * 256;
#pragma unroll
  for (int s = 0; s < 8; ++s) {
    const float4v v0 = *(const float4v*)(xr + s * 32 + g * 8);
    const float4v v1 = *(const float4v*)(xr + s * 32 + g * 8 + 4);
    union { bf16x8 v; unsigned short u[8]; } t;
#pragma unroll
    for (int j = 0; j < 4; ++j) { t.u[j] = f2bf(v0[j]); t.u[4 + j] = f2bf(v1[j]); }
    a[s] = t.v;
  }

  const unsigned short* w0 = Wt;
  const unsigned short* w1 = Wt + 65536;
  const unsigned short* w2 = Wt + 131072;

#pragma unroll
  for (int nfi = 0; nfi < 8; ++nfi) {
    const int nf = nfh * 8 + nfi;
    f32x4 aq = (f32x4){0.f, 0.f, 0.f, 0.f};
    f32x4 ak = (f32x4){0.f, 0.f, 0.f, 0.f};
    f32x4 av = (f32x4){0.f, 0.f, 0.f, 0.f};
    const unsigned short* r0 = w0 + (size_t)(nf * 16 + c) * 256;
    const unsigned short* r1 = w1 + (size_t)(nf * 16 + c) * 256;
    const unsigned short* r2 = w2 + (size_t)(nf * 16 + c) * 256;
#pragma unroll
    for (int s = 0; s < 8; ++s) {
      bf16x8 b0 = *(const bf16x8*)(r0 + s * 32 + g * 8);
      bf16x8 b1 = *(const bf16x8*)(r1 + s * 32 + g * 8);
      bf16x8 b2 = *(const bf16x8*)(r2 + s * 32 + g * 8);
      aq = __builtin_amdgcn_mfma_f32_16x16x32_bf16(a[s], b0, aq, 0, 0, 0);
      ak = __builtin_amdgcn_mfma_f32_16x16x32_bf16(a[s], b1, ak, 0, 0, 0);
      av = __builtin_amdgcn_mfma_f32_16x16x32_bf16(a[s], b2, av, 0, 0, 0);
    }
    const float bql = bq[nf * 16 + c] * (LOG2E / 16.0f);
    const float bkl = bk[nf * 16 + c];
    const float bvl = bv[nf * 16 + c];
#pragma unroll
    for (int r = 0; r < 4; ++r) {
      const int row = row_base + g * 4 + r;
      q_o[(size_t)row * 256 + nf * 16 + c] = f2bf(aq[r] + bql);
      k_o[(size_t)row * 256 + nf * 16 + c] = f2bf(ak[r] + bkl);
      const int b_ = row >> 12, s_ = row & 4095;
      vt_o[((size_t)b_ * 256 + nf * 16 + c) * 4096 + s_] = f2bf(av[r] + bvl);
    }
  }
}

// ---------- kernel 3: causal flash attention ----------
// 512 blocks = 2 halves x 64 tile-slots x 4 batches. Block c (long, qt=127-c/4)
// pairs with c+256 (short, qt=(c-256)/4) on the same CU; step counts sum to 129.
// KVBLK=32, double-buffered 64KB LDS -> 2 blocks/CU AND staging overlaps compute.
// 4 waves = 4 d-quarters: QK^T redundant x4 (MFMA is cheap), softmax fully
// wave-local, NO cross-wave exchange at all; one barrier per kv-step.
__global__ __launch_bounds__(256, 2) void attn_kernel(
    const unsigned short* __restrict__ qg, const unsigned short* __restrict__ kg,
    const unsigned short* __restrict__ vtg, float* __restrict__ out) {
  __shared__ unsigned short Klds[2][32 * 256];   // 2 x 16KB, swizzled image
  __shared__ unsigned short Vlds[2][256 * 32];   // 2 x 16KB, swizzled image

  const int tid = threadIdx.x;
  const int wid = tid >> 6, lane = tid & 63;
  const int hi = lane >> 5, q5 = lane & 31;
  const int dh = wid;                        // wave owns d rows [dh*64, dh*64+64)
  const int bid = blockIdx.x;
  const int c = bid & 255, half = bid >> 8;
  const int qt = half ? (c >> 2) : (127 - (c >> 2));
  const int b = c & 3;
  const int T = qt + 1;

  const unsigned short* qb = qg + (size_t)b * 4096 * 256;
  const unsigned short* kb = kg + (size_t)b * 4096 * 256;
  const unsigned short* vb = vtg + (size_t)b * 256 * 4096;
  float* outb = out + (size_t)b * 4096 * 256;

  const int qrow = qt * 32 + q5;

  // Pre-swizzled global source offsets (LDS dest linear).
  // K[32][256]: row kr, 16B-chunk cs: LDS[kr][cs] = G[kr][cs ^ (kr&7)]
  // V^T[256][32]: row d, 16B-chunk cv(0..3): LDS[d][cv] = G[d][cv ^ ((d>>1)&3)]
  int koff[4], voff[4];
#pragma unroll
  for (int i = 0; i < 4; ++i) {
    const int kr = wid * 8 + i * 2 + (lane >> 5);
    const int cs = (lane & 31) ^ (kr & 7);
    koff[i] = kr * 256 + cs * 8;
    const int d = wid * 64 + i * 16 + (lane >> 2);
    const int cv = (lane & 3) ^ ((d >> 1) & 3);
    voff[i] = d * 4096 + cv * 8;
  }

  auto stage = [&](int bufn, int t) {
    const unsigned short* kp = kb + (size_t)t * 8192;   // 32 rows x 256
    const unsigned short* vp = vb + t * 32;             // 32 kv columns
#pragma unroll
    for (int i = 0; i < 4; ++i)
      gload_lds16(kp + koff[i], &Klds[bufn][(wid * 4 + i) * 512]);
#pragma unroll
    for (int i = 0; i < 4; ++i)
      gload_lds16(vp + voff[i], &Vlds[bufn][(wid * 4 + i) * 512]);
  };

  // Q B-fragments (16): lane: q-col = q5, kdim = s*16 + hi*8 + j
  bf16x8 bqf[16];
  {
    const unsigned short* qr = qb + (size_t)qrow * 256;
#pragma unroll
    for (int s = 0; s < 16; ++s) bqf[s] = *(const bf16x8*)(qr + s * 16 + hi * 8);
  }

  float l = 0.f;                 // per-lane partial row-sum (full kv coverage)
  f32x16 o[2];                   // O^T for 64 d-rows (2 x 32-row blocks)
#pragma unroll
  for (int d = 0; d < 2; ++d)
#pragma unroll
    for (int r = 0; r < 16; ++r) o[d][r] = 0.f;

  const int ksw = (q5 & 7) << 3;          // K row this lane provides = q5
  const int kbase = q5 * 256;

  int kcolr[16];
#pragma unroll
  for (int r = 0; r < 16; ++r) kcolr[r] = (r & 3) + 8 * (r >> 2) + 4 * hi;

  stage(0, 0);
  for (int t = 0; t < T; ++t) {
    const int bufn = t & 1;
    __syncthreads();                       // tile t staged; tile t-1 reads done
    if (t + 1 < T) stage(bufn ^ 1, t + 1); // flies during this step's compute

    // ---- QK^T (swapped): S^T[kv 32][q 32], 2 independent chains ----
    f32x16 sa, sb;
#pragma unroll
    for (int r = 0; r < 16; ++r) { sa[r] = 0.f; sb[r] = 0.f; }
#pragma unroll
    for (int s = 0; s < 8; ++s) {
      bf16x8 ka0 = *(const bf16x8*)(&Klds[bufn][(kbase + s * 16 + hi * 8) ^ ksw]);
      bf16x8 ka1 = *(const bf16x8*)(&Klds[bufn][(kbase + (s + 8) * 16 + hi * 8) ^ ksw]);
      sa = __builtin_amdgcn_mfma_f32_32x32x16_bf16(ka0, bqf[s], sa, 0, 0, 0);
      sb = __builtin_amdgcn_mfma_f32_32x32x16_bf16(ka1, bqf[s + 8], sb, 0, 0, 0);
    }
    f32x16 sc = sa + sb;

    // ---- causal mask (diag step only); scores already in exp2 domain ----
    if (t == T - 1) {
#pragma unroll
      for (int r = 0; r < 16; ++r)
        if (t * 32 + kcolr[r] > qrow) sc[r] = -1e30f;
    }

    // ---- P = exp2(S) (zero-max), partial row-sum ----
    float p[16];
#pragma unroll
    for (int r = 0; r < 16; ++r) p[r] = __builtin_amdgcn_exp2f(sc[r]);
    {
      float s0 = (p[0] + p[1]) + (p[2] + p[3]);
      float s1 = (p[4] + p[5]) + (p[6] + p[7]);
      float s2 = (p[8] + p[9]) + (p[10] + p[11]);
      float s3 = (p[12] + p[13]) + (p[14] + p[15]);
      l += (s0 + s1) + (s2 + s3);
    }

    // ---- build P B-fragments in-register ----
    bf16x8 pfrag[2];
#pragma unroll
    for (int s2 = 0; s2 < 2; ++s2) {
      const int base = s2 * 8;
      unsigned int X = cvtpk(p[base + 0], p[base + 1]);
      unsigned int Y = cvtpk(p[base + 2], p[base + 3]);
      unsigned int Z = cvtpk(p[base + 4], p[base + 5]);
      unsigned int W = cvtpk(p[base + 6], p[base + 7]);
#if __has_builtin(__builtin_amdgcn_permlane32_swap)
      int2v rx = __builtin_amdgcn_permlane32_swap((int)X, (int)Z, false, false);
      int2v ry = __builtin_amdgcn_permlane32_swap((int)Y, (int)W, false, false);
      uint4v u = (uint4v){(unsigned)rx[0], (unsigned)ry[0], (unsigned)rx[1], (unsigned)ry[1]};
#else
      const unsigned int Xp = __shfl_xor((int)X, 32);
      const unsigned int Yp = __shfl_xor((int)Y, 32);
      const unsigned int Zp = __shfl_xor((int)Z, 32);
      const unsigned int Wp = __shfl_xor((int)W, 32);
      uint4v u = (uint4v){hi ? Zp : X, hi ? Wp : Y, hi ? Z : Xp, hi ? W : Yp};
#endif
      pfrag[s2] = __builtin_bit_cast(bf16x8, u);
    }

    // ---- PV (swapped): O^T[64 d][32 q] += V^T_strip . P ----
#pragma unroll
    for (int dblk = 0; dblk < 2; ++dblk) {
      const int drow = dh * 64 + dblk * 32 + q5;
      const int vsw = (drow >> 1) & 3;
#pragma unroll
      for (int s2 = 0; s2 < 2; ++s2) {
        const int chunk = s2 * 2 + hi;
        bf16x8 va = *(const bf16x8*)(&Vlds[bufn][drow * 32 + ((chunk ^ vsw) * 8)]);
        o[dblk] = __builtin_amdgcn_mfma_f32_32x32x16_bf16(va, pfrag[s2], o[dblk], 0, 0, 0);
      }
    }
  }

  // ---- epilogue: wave-local finish, direct stores ----
  l += __shfl_xor(l, 32);
  const float scale = 1.0f / l;
#pragma unroll
  for (int dblk = 0; dblk < 2; ++dblk) {
#pragma unroll
    for (int q2 = 0; q2 < 4; ++q2) {
      float4v val;
#pragma unroll
      for (int e = 0; e < 4; ++e) val[e] = o[dblk][q2 * 4 + e] * scale;
      const int d0 = dh * 64 + dblk * 32 + 8 * q2 + 4 * hi;
      *(float4v*)(outb + (size_t)qrow * 256 + d0) = val;
    }
  }
}

extern "C" void kernel_launch(void* const* d_in, const int* in_sizes, int n_in,
                              void* d_out, int out_size, void* d_ws, size_t ws_size,
                              hipStream_t stream) {
  (void)in_sizes; (void)n_in; (void)out_size; (void)ws_size;
  const float* x  = (const float*)d_in[0];
  const float* Wq = (const float*)d_in[1];
  const float* bq = (const float*)d_in[2];
  const float* Wk = (const float*)d_in[3];
  const float* bk = (const float*)d_in[4];
  const float* Wv = (const float*)d_in[5];
  const float* bv = (const float*)d_in[6];
  float* out = (float*)d_out;

  unsigned short* qs  = (unsigned short*)d_ws;                 // [4][4096][256] bf16
  unsigned short* ks  = qs  + (size_t)16384 * 256;             // [4][4096][256] bf16
  unsigned short* vts = ks  + (size_t)16384 * 256;             // [4][256][4096] bf16 (V^T)
  unsigned short* Wt  = vts + (size_t)16384 * 256;             // [3][256][256]  bf16 (W^T)

  prep_w_kernel<<<dim3(256, 3), 256, 0, stream>>>(Wq, Wk, Wv, Wt);
  proj_kernel<<<dim3(256, 2), 256, 0, stream>>>(x, Wt, bq, bk, bv, qs, ks, vts);
  attn_kernel<<<512, 256, 0, stream>>>(qs, ks, vts, out);
}

// Round 9
// 172.229 us; speedup vs baseline: 1.3892x; 1.2925x over previous
//
#include <hip/hip_runtime.h>
#include <cmath>

#define LOG2E 1.4426950408889634f

typedef __attribute__((ext_vector_type(8))) __bf16 bf16x8;
typedef __attribute__((ext_vector_type(4))) float f32x4;
typedef __attribute__((ext_vector_type(16))) float f32x16;
typedef __attribute__((ext_vector_type(4))) float float4v;
typedef __attribute__((ext_vector_type(4))) unsigned int uint4v;
typedef __attribute__((ext_vector_type(2))) int int2v;

__device__ __forceinline__ unsigned short f2bf(float f) {
  unsigned int u = __builtin_bit_cast(unsigned int, f);
  u += 0x7fffu + ((u >> 16) & 1u);   // RNE
  return (unsigned short)(u >> 16);
}

__device__ __forceinline__ unsigned int cvtpk(float lo, float hi) {
  unsigned int r;
  asm volatile("v_cvt_pk_bf16_f32 %0, %1, %2" : "=v"(r) : "v"(lo), "v"(hi));
  return r;
}

// async global->LDS, 16B per lane; LDS dest = wave-uniform base + lane*16
__device__ __forceinline__ void gload_lds16(const unsigned short* g, unsigned short* l) {
  __builtin_amdgcn_global_load_lds(
      (const __attribute__((address_space(1))) unsigned int*)(const void*)g,
      (__attribute__((address_space(3))) unsigned int*)(void*)l, 16, 0, 0);
}

// ---------- kernel 1: Wt[w][n][k] = bf16(W_w[k][n] * (w==0 ? LOG2E/16 : 1)) ----------
__global__ __launch_bounds__(256) void prep_w_kernel(
    const float* __restrict__ Wq, const float* __restrict__ Wk,
    const float* __restrict__ Wv, unsigned short* __restrict__ Wt) {
  const int w = blockIdx.y, n = blockIdx.x, k = threadIdx.x;
  const float* W = (w == 0) ? Wq : ((w == 1) ? Wk : Wv);
  const float s = (w == 0) ? (LOG2E / 16.0f) : 1.0f;
  Wt[w * 65536 + n * 256 + k] = f2bf(W[k * 256 + n] * s);
}

// ---------- kernel 2: fused q/k/v projection ----------
// grid (256, 2): nf-half split -> 2 blocks/CU; per nf, 3 independent MFMA chains.
__global__ __launch_bounds__(256) void proj_kernel(
    const float* __restrict__ x, const unsigned short* __restrict__ Wt,
    const float* __restrict__ bq, const float* __restrict__ bk,
    const float* __restrict__ bv,
    unsigned short* __restrict__ q_o, unsigned short* __restrict__ k_o,
    unsigned short* __restrict__ vt_o) {
  const int mt = blockIdx.x;           // 256 m-tiles of 64 rows
  const int nfh = blockIdx.y;          // nf half
  const int tid = threadIdx.x;
  const int wid = tid >> 6, lane = tid & 63, g = (lane >> 4) & 3, c = lane & 15;
  const int row_base = mt * 64 + wid * 16;

  bf16x8 a[8];
  const float* xr = x + (size_t)(row_base + c) * 256;
#pragma unroll
  for (int s = 0; s < 8; ++s) {
    const float4v v0 = *(const float4v*)(xr + s * 32 + g * 8);
    const float4v v1 = *(const float4v*)(xr + s * 32 + g * 8 + 4);
    union { bf16x8 v; unsigned short u[8]; } t;
#pragma unroll
    for (int j = 0; j < 4; ++j) { t.u[j] = f2bf(v0[j]); t.u[4 + j] = f2bf(v1[j]); }
    a[s] = t.v;
  }

  const unsigned short* w0 = Wt;
  const unsigned short* w1 = Wt + 65536;
  const unsigned short* w2 = Wt + 131072;

#pragma unroll
  for (int nfi = 0; nfi < 8; ++nfi) {
    const int nf = nfh * 8 + nfi;
    f32x4 aq = (f32x4){0.f, 0.f, 0.f, 0.f};
    f32x4 ak = (f32x4){0.f, 0.f, 0.f, 0.f};
    f32x4 av = (f32x4){0.f, 0.f, 0.f, 0.f};
    const unsigned short* r0 = w0 + (size_t)(nf * 16 + c) * 256;
    const unsigned short* r1 = w1 + (size_t)(nf * 16 + c) * 256;
    const unsigned short* r2 = w2 + (size_t)(nf * 16 + c) * 256;
#pragma unroll
    for (int s = 0; s < 8; ++s) {
      bf16x8 b0 = *(const bf16x8*)(r0 + s * 32 + g * 8);
      bf16x8 b1 = *(const bf16x8*)(r1 + s * 32 + g * 8);
      bf16x8 b2 = *(const bf16x8*)(r2 + s * 32 + g * 8);
      aq = __builtin_amdgcn_mfma_f32_16x16x32_bf16(a[s], b0, aq, 0, 0, 0);
      ak = __builtin_amdgcn_mfma_f32_16x16x32_bf16(a[s], b1, ak, 0, 0, 0);
      av = __builtin_amdgcn_mfma_f32_16x16x32_bf16(a[s], b2, av, 0, 0, 0);
    }
    const float bql = bq[nf * 16 + c] * (LOG2E / 16.0f);
    const float bkl = bk[nf * 16 + c];
    const float bvl = bv[nf * 16 + c];
#pragma unroll
    for (int r = 0; r < 4; ++r) {
      const int row = row_base + g * 4 + r;
      q_o[(size_t)row * 256 + nf * 16 + c] = f2bf(aq[r] + bql);
      k_o[(size_t)row * 256 + nf * 16 + c] = f2bf(ak[r] + bkl);
      const int b_ = row >> 12, s_ = row & 4095;
      vt_o[((size_t)b_ * 256 + nf * 16 + c) * 4096 + s_] = f2bf(av[r] + bvl);
    }
  }
}

// ---------- kernel 3: causal flash attention (R6 structure + phase-split pipeline) ----------
// 512 blocks: block c (long) pairs with c+256 (short) on the same CU; steps sum to 65.
// KVBLK=64, 64KB LDS (single K buf + single V buf) -> 2 blocks/CU.
// Phase-split staging: K(t+1) staged during softmax+PV(t); V(t+1) during QK(t+1).
// Raw s_barrier + counted vmcnt(8) (never 0 mid-loop) keeps loads in flight.
__global__ __launch_bounds__(256, 2) void attn_kernel(
    const unsigned short* __restrict__ qg, const unsigned short* __restrict__ kg,
    const unsigned short* __restrict__ vtg, float* __restrict__ out) {
  __shared__ unsigned short Klds[64 * 256];   // 32KB, swizzled image
  __shared__ unsigned short Vlds[256 * 64];   // 32KB, swizzled image
  __shared__ float llds[2][32];

  const int tid = threadIdx.x;
  const int wid = tid >> 6, lane = tid & 63;
  const int hi = lane >> 5, q5 = lane & 31;
  const int wk = wid & 1, dh = wid >> 1;
  const int bid = blockIdx.x;
  const int half = bid >> 8, c = bid & 255, b = c & 3;
  const int qt = half ? (c >> 2) : (127 - (c >> 2));
  const int T = (qt >> 1) + 1;

  const unsigned short* qb = qg + (size_t)b * 4096 * 256;
  const unsigned short* kb = kg + (size_t)b * 4096 * 256;
  const unsigned short* vb = vtg + (size_t)b * 256 * 4096;
  float* outb = out + (size_t)b * 4096 * 256;

  const int qrow = qt * 32 + q5;

  // Pre-swizzled global source offsets for global_load_lds (LDS dest linear).
  int koff[8], voff[8];
#pragma unroll
  for (int i = 0; i < 8; ++i) {
    const int kr = wid * 16 + i * 2 + (lane >> 5);
    const int c8 = (lane & 31) ^ (kr & 7);
    koff[i] = kr * 256 + c8 * 8;
    const int d = wid * 64 + i * 8 + (lane >> 3);
    const int c8v = (lane & 7) ^ (d & 7);
    voff[i] = d * 4096 + c8v * 8;
  }

  auto stageK = [&](int t) {
    const unsigned short* kp = kb + (size_t)t * 16384;
#pragma unroll
    for (int i = 0; i < 8; ++i)
      gload_lds16(kp + koff[i], &Klds[(wid * 8 + i) * 512]);
  };
  auto stageV = [&](int t) {
    const unsigned short* vp = vb + t * 64;
#pragma unroll
    for (int i = 0; i < 8; ++i)
      gload_lds16(vp + voff[i], &Vlds[(wid * 8 + i) * 512]);
  };

  // Q B-fragments (16): lane: q-col = q5, kdim = s*16 + hi*8 + j
  bf16x8 bqf[16];
  {
    const unsigned short* qr = qb + (size_t)qrow * 256;
#pragma unroll
    for (int s = 0; s < 16; ++s) bqf[s] = *(const bf16x8*)(qr + s * 16 + hi * 8);
  }

  float l = 0.f;                     // per-lane partial row-sum (strip wk)
  f32x16 o[4];                       // O^T for d-half dh
#pragma unroll
  for (int d = 0; d < 4; ++d)
#pragma unroll
    for (int r = 0; r < 16; ++r) o[d][r] = 0.f;

  const int krow = wk * 32 + q5;
  const int ksw = (krow & 7) << 3;
  const int kbase = krow * 256;

  int kcolr[16];
#pragma unroll
  for (int r = 0; r < 16; ++r) kcolr[r] = wk * 32 + (r & 3) + 8 * (r >> 2) + 4 * hi;

  // prologue: both tiles of step 0 in flight (16 outstanding loads)
  stageK(0);
  stageV(0);

  for (int t = 0; t < T; ++t) {
    // ---- wait K(t) arrived (leave V(t)'s 8 loads in flight), sync ----
    asm volatile("s_waitcnt vmcnt(8)" ::: "memory");
    __builtin_amdgcn_s_barrier();
    __builtin_amdgcn_sched_barrier(0);

    // ---- QK^T (swapped): S^T[k strip 32][q 32], 2 indep chains ----
    f32x16 sa, sb;
#pragma unroll
    for (int r = 0; r < 16; ++r) { sa[r] = 0.f; sb[r] = 0.f; }
    __builtin_amdgcn_s_setprio(1);
#pragma unroll
    for (int s = 0; s < 8; ++s) {
      bf16x8 ka0 = *(const bf16x8*)(&Klds[(kbase + s * 16 + hi * 8) ^ ksw]);
      bf16x8 ka1 = *(const bf16x8*)(&Klds[(kbase + (s + 8) * 16 + hi * 8) ^ ksw]);
      sa = __builtin_amdgcn_mfma_f32_32x32x16_bf16(ka0, bqf[s], sa, 0, 0, 0);
      sb = __builtin_amdgcn_mfma_f32_32x32x16_bf16(ka1, bqf[s + 8], sb, 0, 0, 0);
    }
    __builtin_amdgcn_s_setprio(0);
    f32x16 sc = sa + sb;

    // ---- all waves done reading Klds -> safe to overwrite with K(t+1) ----
    asm volatile("s_waitcnt lgkmcnt(0)" ::: "memory");
    __builtin_amdgcn_s_barrier();
    __builtin_amdgcn_sched_barrier(0);
    if (t + 1 < T) stageK(t + 1);    // flies under softmax + PV + next wait

    // ---- causal mask (diag step only); scores already in exp2 domain ----
    if (t == T - 1) {
#pragma unroll
      for (int r = 0; r < 16; ++r)
        if (t * 64 + kcolr[r] > qrow) sc[r] = -1e30f;
    }

    // ---- P = exp2(S) (zero-max), partial row-sum ----
    float p[16];
#pragma unroll
    for (int r = 0; r < 16; ++r) p[r] = __builtin_amdgcn_exp2f(sc[r]);
    {
      float s0 = (p[0] + p[1]) + (p[2] + p[3]);
      float s1 = (p[4] + p[5]) + (p[6] + p[7]);
      float s2 = (p[8] + p[9]) + (p[10] + p[11]);
      float s3 = (p[12] + p[13]) + (p[14] + p[15]);
      l += (s0 + s1) + (s2 + s3);
    }

    // ---- build P B-fragments in-register ----
    bf16x8 pfrag[2];
#pragma unroll
    for (int s2 = 0; s2 < 2; ++s2) {
      const int base = s2 * 8;
      unsigned int X = cvtpk(p[base + 0], p[base + 1]);
      unsigned int Y = cvtpk(p[base + 2], p[base + 3]);
      unsigned int Z = cvtpk(p[base + 4], p[base + 5]);
      unsigned int W = cvtpk(p[base + 6], p[base + 7]);
#if __has_builtin(__builtin_amdgcn_permlane32_swap)
      int2v rx = __builtin_amdgcn_permlane32_swap((int)X, (int)Z, false, false);
      int2v ry = __builtin_amdgcn_permlane32_swap((int)Y, (int)W, false, false);
      uint4v u = (uint4v){(unsigned)rx[0], (unsigned)ry[0], (unsigned)rx[1], (unsigned)ry[1]};
#else
      const unsigned int Xp = __shfl_xor((int)X, 32);
      const unsigned int Yp = __shfl_xor((int)Y, 32);
      const unsigned int Zp = __shfl_xor((int)Z, 32);
      const unsigned int Wp = __shfl_xor((int)W, 32);
      uint4v u = (uint4v){hi ? Zp : X, hi ? Wp : Y, hi ? Z : Xp, hi ? W : Yp};
#endif
      pfrag[s2] = __builtin_bit_cast(bf16x8, u);
    }

    // ---- wait V(t) arrived (K(t+1)'s 8 loads stay in flight), sync ----
    if (t + 1 < T) {
      asm volatile("s_waitcnt vmcnt(8)" ::: "memory");
    } else {
      asm volatile("s_waitcnt vmcnt(0)" ::: "memory");
    }
    __builtin_amdgcn_s_barrier();
    __builtin_amdgcn_sched_barrier(0);

    // ---- PV (swapped): O^T[d-half dh][q 32] += V^T_strip . P ----
    __builtin_amdgcn_s_setprio(1);
#pragma unroll
    for (int dblk = 0; dblk < 4; ++dblk) {
      const int drow = (dh * 4 + dblk) * 32 + q5;
      const int vsw = (drow & 7) << 3;
      const int vbase = drow * 64 + wk * 32;
#pragma unroll
      for (int s2 = 0; s2 < 2; ++s2) {
        bf16x8 va = *(const bf16x8*)(&Vlds[(vbase + s2 * 16 + hi * 8) ^ vsw]);
        o[dblk] = __builtin_amdgcn_mfma_f32_32x32x16_bf16(va, pfrag[s2], o[dblk], 0, 0, 0);
      }
    }
    __builtin_amdgcn_s_setprio(0);

    // ---- all waves done reading Vlds -> safe to overwrite with V(t+1) ----
    asm volatile("s_waitcnt lgkmcnt(0)" ::: "memory");
    __builtin_amdgcn_s_barrier();
    __builtin_amdgcn_sched_barrier(0);
    if (t + 1 < T) stageV(t + 1);    // flies under next QK^T + softmax
  }

  // ---- epilogue: reduce l, cross-wk O combine, write ----
  l += __shfl_xor(l, 32);
  if (dh == 0 && hi == 0) llds[wk][q5] = l;
  __syncthreads();
  const float L = llds[0][q5] + llds[1][q5];
  const float scale = 1.0f / L;

  float* oz = (float*)Klds;          // 32KB: [256 d][32 q] f32
  if (wk == 1) {
#pragma unroll
    for (int dblk = 0; dblk < 4; ++dblk)
#pragma unroll
      for (int r = 0; r < 16; ++r) {
        const int dg = (dh * 4 + dblk) * 32 + (r & 3) + 8 * (r >> 2) + 4 * hi;
        oz[dg * 32 + q5] = o[dblk][r];
      }
  }
  __syncthreads();
  if (wk == 0) {
#pragma unroll
    for (int dblk = 0; dblk < 4; ++dblk) {
#pragma unroll
      for (int q2 = 0; q2 < 4; ++q2) {
        float4v val;
#pragma unroll
        for (int e = 0; e < 4; ++e) {
          const int r = q2 * 4 + e;
          const int dg = (dh * 4 + dblk) * 32 + e + 8 * q2 + 4 * hi;
          val[e] = (o[dblk][r] + oz[dg * 32 + q5]) * scale;
        }
        *(float4v*)(outb + (size_t)qrow * 256 + (dh * 4 + dblk) * 32 + 8 * q2 + 4 * hi) = val;
      }
    }
  }
}

extern "C" void kernel_launch(void* const* d_in, const int* in_sizes, int n_in,
                              void* d_out, int out_size, void* d_ws, size_t ws_size,
                              hipStream_t stream) {
  (void)in_sizes; (void)n_in; (void)out_size; (void)ws_size;
  const float* x  = (const float*)d_in[0];
  const float* Wq = (const float*)d_in[1];
  const float* bq = (const float*)d_in[2];
  const float* Wk = (const float*)d_in[3];
  const float* bk = (const float*)d_in[4];
  const float* Wv = (const float*)d_in[5];
  const float* bv = (const float*)d_in[6];
  float* out = (float*)d_out;

  unsigned short* qs  = (unsigned short*)d_ws;                 // [4][4096][256] bf16
  unsigned short* ks  = qs  + (size_t)16384 * 256;             // [4][4096][256] bf16
  unsigned short* vts = ks  + (size_t)16384 * 256;             // [4][256][4096] bf16 (V^T)
  unsigned short* Wt  = vts + (size_t)16384 * 256;             // [3][256][256]  bf16 (W^T)

  prep_w_kernel<<<dim3(256, 3), 256, 0, stream>>>(Wq, Wk, Wv, Wt);
  proj_kernel<<<dim3(256, 2), 256, 0, stream>>>(x, Wt, bq, bk, bv, qs, ks, vts);
  attn_kernel<<<512, 256, 0, stream>>>(qs, ks, vts, out);
}

// Round 13
// 166.923 us; speedup vs baseline: 1.4334x; 1.0318x over previous
//
#include <hip/hip_runtime.h>
#include <cmath>

#define LOG2E 1.4426950408889634f

typedef __attribute__((ext_vector_type(8))) __bf16 bf16x8;
typedef __attribute__((ext_vector_type(4))) float f32x4;
typedef __attribute__((ext_vector_type(16))) float f32x16;
typedef __attribute__((ext_vector_type(4))) float float4v;
typedef __attribute__((ext_vector_type(4))) unsigned int uint4v;
typedef __attribute__((ext_vector_type(8))) unsigned short ushort8v;
typedef __attribute__((ext_vector_type(2))) int int2v;

__device__ __forceinline__ unsigned short f2bf(float f) {
  unsigned int u = __builtin_bit_cast(unsigned int, f);
  u += 0x7fffu + ((u >> 16) & 1u);   // RNE
  return (unsigned short)(u >> 16);
}

__device__ __forceinline__ unsigned int cvtpk(float lo, float hi) {
  unsigned int r;
  asm volatile("v_cvt_pk_bf16_f32 %0, %1, %2" : "=v"(r) : "v"(lo), "v"(hi));
  return r;
}

// async global->LDS, 16B per lane; LDS dest = wave-uniform base + lane*16
__device__ __forceinline__ void gload_lds16(const unsigned short* g, unsigned short* l) {
  __builtin_amdgcn_global_load_lds(
      (const __attribute__((address_space(1))) unsigned int*)(const void*)g,
      (__attribute__((address_space(3))) unsigned int*)(void*)l, 16, 0, 0);
}

// ---------- kernel 1: Wt[w][n][k] = bf16(W_w[k][n] * (w==0 ? LOG2E/16 : 1)) ----------
__global__ __launch_bounds__(256) void prep_w_kernel(
    const float* __restrict__ Wq, const float* __restrict__ Wk,
    const float* __restrict__ Wv, unsigned short* __restrict__ Wt) {
  const int w = blockIdx.y, n = blockIdx.x, k = threadIdx.x;
  const float* W = (w == 0) ? Wq : ((w == 1) ? Wk : Wv);
  const float s = (w == 0) ? (LOG2E / 16.0f) : 1.0f;
  Wt[w * 65536 + n * 256 + k] = f2bf(W[k * 256 + n] * s);
}

// ---------- kernel 2: fused q/k/v projection, coalesced V^T writeout ----------
// grid (256, 2): nf-half split -> 2 blocks/CU; per nf, 3 independent MFMA chains.
// V results go to a transposed LDS tile [d 128][s 64 (pad 72)], then out as
// 128B-contiguous ushort8 segments (was: 2B scalar scatter at 8KB stride).
__global__ __launch_bounds__(256) void proj_kernel(
    const float* __restrict__ x, const unsigned short* __restrict__ Wt,
    const float* __restrict__ bq, const float* __restrict__ bk,
    const float* __restrict__ bv,
    unsigned short* __restrict__ q_o, unsigned short* __restrict__ k_o,
    unsigned short* __restrict__ vt_o) {
  __shared__ unsigned short vlds[128 * 72];   // 18KB, [d_local][s] pad 72

  const int mt = blockIdx.x;           // 256 m-tiles of 64 rows
  const int nfh = blockIdx.y;          // nf half
  const int tid = threadIdx.x;
  const int wid = tid >> 6, lane = tid & 63, g = (lane >> 4) & 3, c = lane & 15;
  const int row_base = mt * 64 + wid * 16;

  bf16x8 a[8];
  const float* xr = x + (size_t)(row_base + c) * 256;
#pragma unroll
  for (int s = 0; s < 8; ++s) {
    const float4v v0 = *(const float4v*)(xr + s * 32 + g * 8);
    const float4v v1 = *(const float4v*)(xr + s * 32 + g * 8 + 4);
    union { bf16x8 v; unsigned short u[8]; } t;
#pragma unroll
    for (int j = 0; j < 4; ++j) { t.u[j] = f2bf(v0[j]); t.u[4 + j] = f2bf(v1[j]); }
    a[s] = t.v;
  }

  const unsigned short* w0 = Wt;
  const unsigned short* w1 = Wt + 65536;
  const unsigned short* w2 = Wt + 131072;

#pragma unroll
  for (int nfi = 0; nfi < 8; ++nfi) {
    const int nf = nfh * 8 + nfi;
    f32x4 aq = (f32x4){0.f, 0.f, 0.f, 0.f};
    f32x4 ak = (f32x4){0.f, 0.f, 0.f, 0.f};
    f32x4 av = (f32x4){0.f, 0.f, 0.f, 0.f};
    const unsigned short* r0 = w0 + (size_t)(nf * 16 + c) * 256;
    const unsigned short* r1 = w1 + (size_t)(nf * 16 + c) * 256;
    const unsigned short* r2 = w2 + (size_t)(nf * 16 + c) * 256;
#pragma unroll
    for (int s = 0; s < 8; ++s) {
      bf16x8 b0 = *(const bf16x8*)(r0 + s * 32 + g * 8);
      bf16x8 b1 = *(const bf16x8*)(r1 + s * 32 + g * 8);
      bf16x8 b2 = *(const bf16x8*)(r2 + s * 32 + g * 8);
      aq = __builtin_amdgcn_mfma_f32_16x16x32_bf16(a[s], b0, aq, 0, 0, 0);
      ak = __builtin_amdgcn_mfma_f32_16x16x32_bf16(a[s], b1, ak, 0, 0, 0);
      av = __builtin_amdgcn_mfma_f32_16x16x32_bf16(a[s], b2, av, 0, 0, 0);
    }
    const float bql = bq[nf * 16 + c] * (LOG2E / 16.0f);
    const float bkl = bk[nf * 16 + c];
    const float bvl = bv[nf * 16 + c];
#pragma unroll
    for (int r = 0; r < 4; ++r) {
      const int row = row_base + g * 4 + r;
      q_o[(size_t)row * 256 + nf * 16 + c] = f2bf(aq[r] + bql);
      k_o[(size_t)row * 256 + nf * 16 + c] = f2bf(ak[r] + bkl);
      // V -> transposed LDS tile (d_local = nfi*16+c, s_local = row within tile)
      vlds[(nfi * 16 + c) * 72 + (wid * 16 + g * 4 + r)] = f2bf(av[r] + bvl);
    }
  }

  __syncthreads();

  // coalesced V^T writeout: 128 d-rows x 64 s, 16B per thread-chunk
  const int bb = mt >> 6;                       // batch
  const int s0 = (mt & 63) * 64;                // kv-position base
  unsigned short* vout = vt_o + ((size_t)bb * 256 + nfh * 128) * 4096 + s0;
#pragma unroll
  for (int it = 0; it < 4; ++it) {
    const int idx = it * 256 + tid;
    const int dl = idx >> 3, s8 = idx & 7;
    ushort8v val = *(const ushort8v*)(vlds + dl * 72 + s8 * 8);
    *(ushort8v*)(vout + (size_t)dl * 4096 + s8 * 8) = val;
  }
}

// ---------- kernel 3: causal flash attention (R6-proven structure) ----------
// 512 blocks = 2 halves x 64 tile-slots x 4 batches. Block c (long, qt=127-c/4)
// pairs with c+256 (short, qt=(c-256)/4) on the same CU; step counts sum to 65.
// KVBLK=64, 64KB LDS single-buffer -> 2 blocks/CU (TLP hides staging + chains).
// Waves (wk kv-strip, dh d-half); QK redundant across dh; zero-max softmax;
// P in-register via cvt_pk + permlane32_swap; O^T = mfma(V^T, P).
__global__ __launch_bounds__(256, 2) void attn_kernel(
    const unsigned short* __restrict__ qg, const unsigned short* __restrict__ kg,
    const unsigned short* __restrict__ vtg, float* __restrict__ out) {
  __shared__ unsigned short Klds[64 * 256];   // 32KB, swizzled image
  __shared__ unsigned short Vlds[256 * 64];   // 32KB, swizzled image
  __shared__ float llds[2][32];

  const int tid = threadIdx.x;
  const int wid = tid >> 6, lane = tid & 63;
  const int hi = lane >> 5, q5 = lane & 31;
  const int wk = wid & 1, dh = wid >> 1;
  const int bid = blockIdx.x;
  const int half = bid >> 8, c = bid & 255, b = c & 3;
  const int qt = half ? (c >> 2) : (127 - (c >> 2));
  const int T = (qt >> 1) + 1;

  const unsigned short* qb = qg + (size_t)b * 4096 * 256;
  const unsigned short* kb = kg + (size_t)b * 4096 * 256;
  const unsigned short* vb = vtg + (size_t)b * 256 * 4096;
  float* outb = out + (size_t)b * 4096 * 256;

  const int qrow = qt * 32 + q5;

  // Pre-swizzled global source offsets for global_load_lds (LDS dest linear).
  int koff[8], voff[8];
#pragma unroll
  for (int i = 0; i < 8; ++i) {
    const int kr = wid * 16 + i * 2 + (lane >> 5);
    const int c8 = (lane & 31) ^ (kr & 7);
    koff[i] = kr * 256 + c8 * 8;
    const int d = wid * 64 + i * 8 + (lane >> 3);
    const int c8v = (lane & 7) ^ (d & 7);
    voff[i] = d * 4096 + c8v * 8;
  }

  auto stage = [&](int t) {
    const unsigned short* kp = kb + (size_t)t * 16384;
    const unsigned short* vp = vb + t * 64;
#pragma unroll
    for (int i = 0; i < 8; ++i)
      gload_lds16(kp + koff[i], &Klds[(wid * 8 + i) * 512]);
#pragma unroll
    for (int i = 0; i < 8; ++i)
      gload_lds16(vp + voff[i], &Vlds[(wid * 8 + i) * 512]);
  };

  // Q B-fragments (16): lane: q-col = q5, kdim = s*16 + hi*8 + j
  bf16x8 bqf[16];
  {
    const unsigned short* qr = qb + (size_t)qrow * 256;
#pragma unroll
    for (int s = 0; s < 16; ++s) bqf[s] = *(const bf16x8*)(qr + s * 16 + hi * 8);
  }

  float l = 0.f;                     // per-lane partial row-sum (strip wk)
  f32x16 o[4];                       // O^T for d-half dh
#pragma unroll
  for (int d = 0; d < 4; ++d)
#pragma unroll
    for (int r = 0; r < 16; ++r) o[d][r] = 0.f;

  const int krow = wk * 32 + q5;
  const int ksw = (krow & 7) << 3;
  const int kbase = krow * 256;

  int kcolr[16];
#pragma unroll
  for (int r = 0; r < 16; ++r) kcolr[r] = wk * 32 + (r & 3) + 8 * (r >> 2) + 4 * hi;

  stage(0);
  for (int t = 0; t < T; ++t) {
    __syncthreads();                 // drains vmcnt -> K/V tile t ready

    // ---- QK^T (swapped): S^T[k strip 32][q 32], 2 indep chains ----
    f32x16 sa, sb;
#pragma unroll
    for (int r = 0; r < 16; ++r) { sa[r] = 0.f; sb[r] = 0.f; }
#pragma unroll
    for (int s = 0; s < 8; ++s) {
      bf16x8 ka0 = *(const bf16x8*)(&Klds[(kbase + s * 16 + hi * 8) ^ ksw]);
      bf16x8 ka1 = *(const bf16x8*)(&Klds[(kbase + (s + 8) * 16 + hi * 8) ^ ksw]);
      sa = __builtin_amdgcn_mfma_f32_32x32x16_bf16(ka0, bqf[s], sa, 0, 0, 0);
      sb = __builtin_amdgcn_mfma_f32_32x32x16_bf16(ka1, bqf[s + 8], sb, 0, 0, 0);
    }
    f32x16 sc = sa + sb;

    // ---- causal mask (diag step only); scores already in exp2 domain ----
    if (t == T - 1) {
#pragma unroll
      for (int r = 0; r < 16; ++r)
        if (t * 64 + kcolr[r] > qrow) sc[r] = -1e30f;
    }

    // ---- P = exp2(S) (zero-max), partial row-sum ----
    float p[16];
#pragma unroll
    for (int r = 0; r < 16; ++r) p[r] = __builtin_amdgcn_exp2f(sc[r]);
    {
      float s0 = (p[0] + p[1]) + (p[2] + p[3]);
      float s1 = (p[4] + p[5]) + (p[6] + p[7]);
      float s2 = (p[8] + p[9]) + (p[10] + p[11]);
      float s3 = (p[12] + p[13]) + (p[14] + p[15]);
      l += (s0 + s1) + (s2 + s3);
    }

    // ---- build P B-fragments in-register ----
    bf16x8 pfrag[2];
#pragma unroll
    for (int s2 = 0; s2 < 2; ++s2) {
      const int base = s2 * 8;
      unsigned int X = cvtpk(p[base + 0], p[base + 1]);
      unsigned int Y = cvtpk(p[base + 2], p[base + 3]);
      unsigned int Z = cvtpk(p[base + 4], p[base + 5]);
      unsigned int W = cvtpk(p[base + 6], p[base + 7]);
#if __has_builtin(__builtin_amdgcn_permlane32_swap)
      int2v rx = __builtin_amdgcn_permlane32_swap((int)X, (int)Z, false, false);
      int2v ry = __builtin_amdgcn_permlane32_swap((int)Y, (int)W, false, false);
      uint4v u = (uint4v){(unsigned)rx[0], (unsigned)ry[0], (unsigned)rx[1], (unsigned)ry[1]};
#else
      const unsigned int Xp = __shfl_xor((int)X, 32);
      const unsigned int Yp = __shfl_xor((int)Y, 32);
      const unsigned int Zp = __shfl_xor((int)Z, 32);
      const unsigned int Wp = __shfl_xor((int)W, 32);
      uint4v u = (uint4v){hi ? Zp : X, hi ? Wp : Y, hi ? Z : Xp, hi ? W : Yp};
#endif
      pfrag[s2] = __builtin_bit_cast(bf16x8, u);
    }

    // ---- PV (swapped): O^T[d-half dh][q 32] += V^T_strip . P ----
#pragma unroll
    for (int dblk = 0; dblk < 4; ++dblk) {
      const int drow = (dh * 4 + dblk) * 32 + q5;
      const int vsw = (drow & 7) << 3;
      const int vbase = drow * 64 + wk * 32;
#pragma unroll
      for (int s2 = 0; s2 < 2; ++s2) {
        bf16x8 va = *(const bf16x8*)(&Vlds[(vbase + s2 * 16 + hi * 8) ^ vsw]);
        o[dblk] = __builtin_amdgcn_mfma_f32_32x32x16_bf16(va, pfrag[s2], o[dblk], 0, 0, 0);
      }
    }

    if (t + 1 < T) {
      __syncthreads();               // all waves done reading tile t
      stage(t + 1);                  // overwrite buffer with tile t+1
    }
  }

  // ---- epilogue: reduce l, cross-wk O combine, write ----
  l += __shfl_xor(l, 32);
  if (dh == 0 && hi == 0) llds[wk][q5] = l;
  __syncthreads();                   // l visible; also all K/V reads done
  const float L = llds[0][q5] + llds[1][q5];
  const float scale = 1.0f / L;

  float* oz = (float*)Klds;          // 32KB: [256 d][32 q] f32
  if (wk == 1) {
#pragma unroll
    for (int dblk = 0; dblk < 4; ++dblk)
#pragma unroll
      for (int r = 0; r < 16; ++r) {
        const int dg = (dh * 4 + dblk) * 32 + (r & 3) + 8 * (r >> 2) + 4 * hi;
        oz[dg * 32 + q5] = o[dblk][r];
      }
  }
  __syncthreads();
  if (wk == 0) {
#pragma unroll
    for (int dblk = 0; dblk < 4; ++dblk) {
#pragma unroll
      for (int q2 = 0; q2 < 4; ++q2) {
        float4v val;
#pragma unroll
        for (int e = 0; e < 4; ++e) {
          const int r = q2 * 4 + e;
          const int dg = (dh * 4 + dblk) * 32 + e + 8 * q2 + 4 * hi;
          val[e] = (o[dblk][r] + oz[dg * 32 + q5]) * scale;
        }
        *(float4v*)(outb + (size_t)qrow * 256 + (dh * 4 + dblk) * 32 + 8 * q2 + 4 * hi) = val;
      }
    }
  }
}

extern "C" void kernel_launch(void* const* d_in, const int* in_sizes, int n_in,
                              void* d_out, int out_size, void* d_ws, size_t ws_size,
                              hipStream_t stream) {
  (void)in_sizes; (void)n_in; (void)out_size; (void)ws_size;
  const float* x  = (const float*)d_in[0];
  const float* Wq = (const float*)d_in[1];
  const float* bq = (const float*)d_in[2];
  const float* Wk = (const float*)d_in[3];
  const float* bk = (const float*)d_in[4];
  const float* Wv = (const float*)d_in[5];
  const float* bv = (const float*)d_in[6];
  float* out = (float*)d_out;

  unsigned short* qs  = (unsigned short*)d_ws;                 // [4][4096][256] bf16
  unsigned short* ks  = qs  + (size_t)16384 * 256;             // [4][4096][256] bf16
  unsigned short* vts = ks  + (size_t)16384 * 256;             // [4][256][4096] bf16 (V^T)
  unsigned short* Wt  = vts + (size_t)16384 * 256;             // [3][256][256]  bf16 (W^T)

  prep_w_kernel<<<dim3(256, 3), 256, 0, stream>>>(Wq, Wk, Wv, Wt);
  proj_kernel<<<dim3(256, 2), 256, 0, stream>>>(x, Wt, bq, bk, bv, qs, ks, vts);
  attn_kernel<<<512, 256, 0, stream>>>(qs, ks, vts, out);
}